// Round 1
// baseline (2296.462 us; speedup 1.0000x reference)
//
#include <hip/hip_runtime.h>
#include <hip/hip_bf16.h>

// SimpleRNN fused persistent kernel for MI355X (gfx950).
// T=512 steps, B=1024, IN=128, H=256, OUT=4, K=IN+H=384.
// Key insight: recurrence is independent across batch rows -> 64 WGs of 16
// batch rows each run all 512 steps with only workgroup barriers.
// Weights live in VGPRs as loop-invariant MFMA B-fragments (17 col-tiles:
// 16 h-tiles + 1 logits tile padded with zero columns).

#define TT    512
#define BBAT  1024
#define INDIM 128
#define HDIM  256
#define KDIM  384
#define LDK   392   // LDS row stride in bf16 elems: 784 B, 16B-aligned, bank-stride 4 (conflict-free-ish)
#define NB    16    // batch rows per workgroup

typedef __attribute__((ext_vector_type(8))) __bf16 bf16x8;
typedef __attribute__((ext_vector_type(4))) float  fx4;

__device__ __forceinline__ __bf16 f2bf(float f) {
  // round-to-nearest-even fp32 -> bf16 (no NaN handling needed; values bounded)
  unsigned u = __builtin_bit_cast(unsigned, f);
  unsigned short r = (unsigned short)((u + 0x7FFFu + ((u >> 16) & 1u)) >> 16);
  return __builtin_bit_cast(__bf16, r);
}

__global__ __launch_bounds__(256, 1) void rnn_fused(
    const float* __restrict__ inp,     // [T,B,IN]
    const float* __restrict__ hidden,  // [B,H]
    const float* __restrict__ Wih,     // [H, K]
    const float* __restrict__ bih,     // [H]
    const float* __restrict__ Wio,     // [4, K]
    const float* __restrict__ bio,     // [4]
    const float* __restrict__ act,     // [4, H]
    float* __restrict__ out)           // [T*B*4] ++ [B*H]
{
  __shared__ __align__(16) __bf16 comb[NB * LDK];  // [x_t | h_t] bf16
  __shared__ float lgt[NB * 4];
  __shared__ int   qidx[NB];
  __shared__ float biasH[HDIM];
  __shared__ __align__(16) fx4 actp[HDIM];         // actp[n][j] = 1 + act[j][n]
  __shared__ float biasO[4];

  const int tid  = threadIdx.x;
  const int wave = tid >> 6;
  const int lane = tid & 63;
  const int l15  = lane & 15;   // MFMA: A-row (m) for A-frag, B-col (n) for B-frag, D-col (n)
  const int qq   = lane >> 4;   // MFMA quad
  const int b0   = blockIdx.x * NB;

  float* outs = out;
  float* hs0  = out + (long)TT * BBAT * 4;

  // ---- one-time LDS init ----
  if (tid < HDIM) {
    biasH[tid] = bih[tid];
    fx4 v;
    v[0] = 1.0f + act[0 * HDIM + tid];
    v[1] = 1.0f + act[1 * HDIM + tid];
    v[2] = 1.0f + act[2 * HDIM + tid];
    v[3] = 1.0f + act[3 * HDIM + tid];
    actp[tid] = v;
  }
  if (tid < 4) biasO[tid] = bio[tid];

  {
    const int row = tid >> 4;   // 0..15
    const int cg  = tid & 15;
    // h0 (given initial hidden state) -> comb[:,128:384]
    const float* hp = hidden + (b0 + row) * HDIM + cg * 16;
    bf16x8 s0, s1;
#pragma unroll
    for (int i = 0; i < 8; ++i) s0[i] = f2bf(hp[i]);
#pragma unroll
    for (int i = 0; i < 8; ++i) s1[i] = f2bf(hp[8 + i]);
    *(bf16x8*)&comb[row * LDK + INDIM + cg * 16]     = s0;
    *(bf16x8*)&comb[row * LDK + INDIM + cg * 16 + 8] = s1;
    // x[0] -> comb[:,0:128]
    const float* xp = inp + (long)(b0 + row) * INDIM + cg * 8;
    bf16x8 sx;
#pragma unroll
    for (int i = 0; i < 8; ++i) sx[i] = f2bf(xp[i]);
    *(bf16x8*)&comb[row * LDK + cg * 8] = sx;
  }

  // ---- load loop-invariant weight B-fragments into VGPRs ----
  // tiles 0..15: W_i2h columns; tile 16: W_i2o (rows 256..259), rows 260..271 zero.
  const int myNT = (wave == 3) ? 5 : 4;
  bf16x8 Bfr[5][12];
#pragma unroll
  for (int j = 0; j < 5; ++j) {
    const int tile = (j < 4) ? (wave * 4 + j) : 16;
    if (j < myNT) {
      const int row = tile * 16 + l15;
#pragma unroll
      for (int kc = 0; kc < 12; ++kc) {
        const int k0 = kc * 32 + qq * 8;
        bf16x8 f;
        if (row < 260) {
          const float* wp = (row < 256) ? (Wih + (long)row * KDIM + k0)
                                        : (Wio + (long)(row - 256) * KDIM + k0);
#pragma unroll
          for (int i = 0; i < 8; ++i) f[i] = f2bf(wp[i]);
        } else {
#pragma unroll
          for (int i = 0; i < 8; ++i) f[i] = __builtin_bit_cast(__bf16, (unsigned short)0);
        }
        Bfr[j][kc] = f;
      }
    }
  }
  __syncthreads();

  // ---- 512 sequential steps ----
#pragma unroll 1
  for (int t = 0; t < TT; ++t) {
    // prefetch x[t+1] into registers (landed by epilogue time)
    fx4 xa, xb;
    const int xrow = tid >> 4, xcg = tid & 15;
    if (t + 1 < TT) {
      const float* xp = inp + ((long)(t + 1) * BBAT + b0 + xrow) * INDIM + xcg * 8;
      xa = *(const fx4*)xp;
      xb = *(const fx4*)(xp + 4);
    }

    fx4 acc[5];
#pragma unroll
    for (int j = 0; j < 5; ++j) { fx4 z = {0.f, 0.f, 0.f, 0.f}; acc[j] = z; }

    // K-loop: A-frag from LDS (A[m=l15][k=kc*32+qq*8+i]), B-frags from VGPRs
#pragma unroll
    for (int kc = 0; kc < 12; ++kc) {
      bf16x8 a = *(const bf16x8*)&comb[l15 * LDK + kc * 32 + qq * 8];
#pragma unroll
      for (int j = 0; j < 5; ++j)
        if (j < myNT)
          acc[j] = __builtin_amdgcn_mfma_f32_16x16x32_bf16(a, Bfr[j][kc], acc[j], 0, 0, 0);
    }

    // wave 3 owns the logits tile: write logits, argmax (first-index ties), store outs
    if (wave == 3) {
      if (l15 < 4) {
#pragma unroll
        for (int r = 0; r < 4; ++r)
          lgt[(qq * 4 + r) * 4 + l15] = acc[4][r] + biasO[l15];
      }
      if (lane < NB) {
        const float v0 = lgt[lane * 4 + 0], v1 = lgt[lane * 4 + 1];
        const float v2 = lgt[lane * 4 + 2], v3 = lgt[lane * 4 + 3];
        int qi = 0; float bv = v0;
        if (v1 > bv) { bv = v1; qi = 1; }
        if (v2 > bv) { bv = v2; qi = 2; }
        if (v3 > bv) { bv = v3; qi = 3; }
        qidx[lane] = qi;
      }
      // 64 contiguous floats: outs[t, b0..b0+15, 0..3]
      outs[((long)t * BBAT + b0) * 4 + lane] = lgt[lane];
    }
    __syncthreads();   // A-frags consumed, qidx ready -> safe to overwrite comb

    int qs[4];
#pragma unroll
    for (int r = 0; r < 4; ++r) qs[r] = qidx[qq * 4 + r];

    // epilogue: y = acc+bias -> tanh -> (t==0: store hs0 pre-gate) -> gate -> comb
#pragma unroll
    for (int j = 0; j < 4; ++j) {
      const int tile = wave * 4 + j;
      const int n = tile * 16 + l15;
      const float bn = biasH[n];
      const fx4 an = actp[n];
#pragma unroll
      for (int r = 0; r < 4; ++r) {
        const int m = qq * 4 + r;              // D layout: row m = qq*4+r, col n = l15
        float y = acc[j][r] + bn;
        y = fminf(fmaxf(y, -15.0f), 15.0f);    // tanh(+-15)==+-1 at fp32; avoids exp overflow
        const float e  = __expf(2.0f * y);
        const float th = 1.0f - 2.0f / (e + 1.0f);
        if (t == 0) hs0[(long)(b0 + m) * HDIM + n] = th;
        const int qi = qs[r];
        const float gv = (qi == 0) ? an[0] : (qi == 1) ? an[1] : (qi == 2) ? an[2] : an[3];
        comb[m * LDK + INDIM + n] = f2bf(th * gv);
      }
    }
    // write prefetched x[t+1] into comb x-region
    if (t + 1 < TT) {
      bf16x8 s;
      s[0] = f2bf(xa[0]); s[1] = f2bf(xa[1]); s[2] = f2bf(xa[2]); s[3] = f2bf(xa[3]);
      s[4] = f2bf(xb[0]); s[5] = f2bf(xb[1]); s[6] = f2bf(xb[2]); s[7] = f2bf(xb[3]);
      *(bf16x8*)&comb[xrow * LDK + xcg * 8] = s;
    }
    __syncthreads();   // comb[t+1] ready
  }
}

extern "C" void kernel_launch(void* const* d_in, const int* in_sizes, int n_in,
                              void* d_out, int out_size, void* d_ws, size_t ws_size,
                              hipStream_t stream) {
  const float* inp    = (const float*)d_in[0];
  const float* hidden = (const float*)d_in[1];
  const float* Wih    = (const float*)d_in[2];
  const float* bih    = (const float*)d_in[3];
  const float* Wio    = (const float*)d_in[4];
  const float* bio    = (const float*)d_in[5];
  const float* act    = (const float*)d_in[6];
  float* out = (float*)d_out;
  rnn_fused<<<dim3(BBAT / NB), dim3(256), 0, stream>>>(
      inp, hidden, Wih, bih, Wio, bio, act, out);
}

// Round 2
// 991.324 us; speedup vs baseline: 2.3166x; 2.3166x over previous
//
#include <hip/hip_runtime.h>
#include <hip/hip_bf16.h>

// SimpleRNN fused persistent kernel, round 2.
// T=512, B=1024, IN=128, H=256, OUT=4, K=384. 64 WGs x 16 batch rows.
// Latency-bound serial chain -> minimize per-step critical path:
//  - weights as MFMA A-operand, comb as B-operand: D[row=output][col=batch].
//    -> h writeback = 4x ds_write_b64/lane; logits of a batch row land in ONE
//       lane -> in-register argmax + single shfl broadcast (no LDS roundtrip).
//  - ping-pong comb buffers -> ONE barrier/step.
//  - custom barrier (s_waitcnt lgkmcnt(0); s_barrier): no vmcnt(0) drain, so
//    x-prefetch loads and outs stores stay in flight across the barrier.
//  - bias pre-scaled by 2*log2(e) in regs; tanh = 1 - 2/(exp2(z)+1), no clamp
//    (e=inf -> rcp=0 -> th=1 is the correct limit).

#define TT    512
#define BBAT  1024
#define INDIM 128
#define HDIM  256
#define KDIM  384
#define LDK   392   // bf16 elems/row: 784 B -> 196 dwords == 4 (mod 32) bank rotation
#define NB    16
#define GPAD  264   // gate table row pad: qi*264 dwords -> 8-bank rotation per qi

typedef __attribute__((ext_vector_type(8))) __bf16 bf16x8;
typedef __attribute__((ext_vector_type(4))) float  fx4;
typedef __attribute__((ext_vector_type(4))) unsigned int ui4;

__device__ __forceinline__ __bf16 f2bf(float f) {
  unsigned u = __builtin_bit_cast(unsigned, f);
  unsigned short r = (unsigned short)((u + 0x7FFFu + ((u >> 16) & 1u)) >> 16);
  return __builtin_bit_cast(__bf16, r);
}

// LDS-only barrier: waits DS ops, does NOT drain vmcnt (global loads/stores
// in flight are private to this wave; cross-wave comms are LDS-only).
__device__ __forceinline__ void ldsbar() {
  asm volatile("s_waitcnt lgkmcnt(0)\n\ts_barrier" ::: "memory");
}

__global__ __launch_bounds__(256, 1) void rnn_fused(
    const float* __restrict__ inp,     // [T,B,IN]
    const float* __restrict__ hidden,  // [B,H]
    const float* __restrict__ Wih,     // [H, K]
    const float* __restrict__ bih,     // [H]
    const float* __restrict__ Wio,     // [4, K]
    const float* __restrict__ bio,     // [4]
    const float* __restrict__ act,     // [4, H]
    float* __restrict__ out)           // [T*B*4] ++ [B*H]
{
  __shared__ __align__(16) __bf16 cb[2][NB * LDK];  // ping-pong [batch row][k]
  __shared__ __align__(16) float  gt[4 * GPAD];     // gt[qi][o] = 1 + act[qi][o]

  const int tid  = threadIdx.x;
  const int wave = tid >> 6;
  const int lane = tid & 63;
  const int l15  = lane & 15;   // batch row (B-frag col / D col); weight A-frag row
  const int qq   = lane >> 4;
  const int b0   = blockIdx.x * NB;

  float* outs = out;
  float* hs0  = out + (long)TT * BBAT * 4;

  const float C2 = 2.8853900817779268f;  // 2*log2(e)

  // ---- one-time init: gate table, initial comb (h0|x0) into cb[0] ----
#pragma unroll
  for (int qi = 0; qi < 4; ++qi)
    gt[qi * GPAD + tid] = 1.0f + act[qi * HDIM + tid];

  {
    const int row = tid >> 4;   // batch row 0..15
    const int cg  = tid & 15;
    // h0 -> cb[0][row][128+cg*16 .. +15]
    const float* hp = hidden + (long)(b0 + row) * HDIM + cg * 16;
    union { ui4 v; __hip_bfloat162 h2[4]; } pk;
#pragma unroll
    for (int half = 0; half < 2; ++half) {
      pk.h2[0] = __float22bfloat162_rn(make_float2(hp[half*8+0], hp[half*8+1]));
      pk.h2[1] = __float22bfloat162_rn(make_float2(hp[half*8+2], hp[half*8+3]));
      pk.h2[2] = __float22bfloat162_rn(make_float2(hp[half*8+4], hp[half*8+5]));
      pk.h2[3] = __float22bfloat162_rn(make_float2(hp[half*8+6], hp[half*8+7]));
      *(ui4*)&cb[0][row * LDK + INDIM + cg * 16 + half * 8] = pk.v;
    }
    // x0 -> cb[0][row][cg*8 .. +7]
    const float* xp = inp + (long)(b0 + row) * INDIM + cg * 8;
    pk.h2[0] = __float22bfloat162_rn(make_float2(xp[0], xp[1]));
    pk.h2[1] = __float22bfloat162_rn(make_float2(xp[2], xp[3]));
    pk.h2[2] = __float22bfloat162_rn(make_float2(xp[4], xp[5]));
    pk.h2[3] = __float22bfloat162_rn(make_float2(xp[6], xp[7]));
    *(ui4*)&cb[0][row * LDK + cg * 8] = pk.v;
  }

  // ---- loop-invariant weight A-fragments (5 tiles/wave: 4 h-tiles + logits) ----
  // A[m=tile*16+l15][k=kc*32+qq*8+i]; tile 16 rows >=260 are zero.
  bf16x8 Wfr[5][12];
#pragma unroll
  for (int j = 0; j < 5; ++j) {
    const int tile = (j < 4) ? (wave * 4 + j) : 16;
    const int row  = tile * 16 + l15;
#pragma unroll
    for (int kc = 0; kc < 12; ++kc) {
      const int k0 = kc * 32 + qq * 8;
      bf16x8 f;
      if (row < 260) {
        const float* wp = (row < 256) ? (Wih + (long)row * KDIM + k0)
                                      : (Wio + (long)(row - 256) * KDIM + k0);
#pragma unroll
        for (int i = 0; i < 8; ++i) f[i] = f2bf(wp[i]);
      } else {
#pragma unroll
        for (int i = 0; i < 8; ++i) f[i] = __builtin_bit_cast(__bf16, (unsigned short)0);
      }
      Wfr[j][kc] = f;
    }
  }

  // per-lane bias (pre-scaled by C2) for the 4 h-tiles, and output bias
  fx4 cbz[4];
#pragma unroll
  for (int j = 0; j < 4; ++j) {
    const int o0 = (wave * 4 + j) * 16 + qq * 4;
    const fx4 b = *(const fx4*)&bih[o0];
    cbz[j] = b * C2;
  }
  const fx4 bo = *(const fx4*)&bio[0];

  __syncthreads();

  // ---- one RNN step ----
  auto stepf = [&](int t, const __bf16* __restrict__ cbR, __bf16* __restrict__ cbW) {
    // prefetch x[t+1] (consumed at end of this step -> ~full step of cover)
    fx4 xa, xb;
    const int xrow = tid >> 4, xcg = tid & 15;
    const bool hasx = (t + 1 < TT);
    if (hasx) {
      const float* xp = inp + ((long)(t + 1) * BBAT + b0 + xrow) * INDIM + xcg * 8;
      xa = *(const fx4*)xp;
      xb = *(const fx4*)(xp + 4);
    }

    fx4 acc[5];
#pragma unroll
    for (int j = 0; j < 5; ++j) { fx4 z = {0.f, 0.f, 0.f, 0.f}; acc[j] = z; }

    const __bf16* arow = cbR + l15 * LDK + qq * 8;
#pragma unroll
    for (int kc = 0; kc < 12; ++kc) {
      bf16x8 bfrag = *(const bf16x8*)(arow + kc * 32);
#pragma unroll
      for (int j = 0; j < 5; ++j)
        acc[j] = __builtin_amdgcn_mfma_f32_16x16x32_bf16(Wfr[j][kc], bfrag, acc[j], 0, 0, 0);
    }

    // logits: lane (qq=0, l15) holds all 4 logits of batch row l15
    fx4 lg = acc[4] + bo;
    int qi = 0; float bv = lg[0];
    if (lg[1] > bv) { bv = lg[1]; qi = 1; }
    if (lg[2] > bv) { bv = lg[2]; qi = 2; }
    if (lg[3] > bv) { bv = lg[3]; qi = 3; }
    if (wave == 3 && qq == 0)
      *(fx4*)&outs[((long)t * BBAT + b0 + l15) * 4] = lg;   // coalesced 256B
    const int q = __shfl(qi, l15, 64);   // broadcast row-l15 argmax to all qq

    // epilogue: th = tanh(acc+bias) = 1 - 2/(exp2(C2*acc + C2*b) + 1)
#pragma unroll
    for (int j = 0; j < 4; ++j) {
      const int o0 = (wave * 4 + j) * 16 + qq * 4;
      fx4 z = acc[j] * C2 + cbz[j];
      fx4 th;
#pragma unroll
      for (int r = 0; r < 4; ++r) {
        const float e  = __builtin_amdgcn_exp2f(z[r]);
        const float rc = __builtin_amdgcn_rcpf(e + 1.0f);
        th[r] = fmaf(-2.0f, rc, 1.0f);
      }
      if (t == 0)
        *(fx4*)&hs0[(long)(b0 + l15) * HDIM + o0] = th;     // hs[0] pre-gate
      const fx4 g = *(const fx4*)&gt[q * GPAD + o0];        // conflict-free b128
      const fx4 hg = th * g;
      union { unsigned long long u; __hip_bfloat162 h2[2]; } pk;
      pk.h2[0] = __float22bfloat162_rn(make_float2(hg[0], hg[1]));
      pk.h2[1] = __float22bfloat162_rn(make_float2(hg[2], hg[3]));
      *(unsigned long long*)(cbW + l15 * LDK + INDIM + o0) = pk.u;  // b64 write
    }

    // write prefetched x[t+1]
    if (hasx) {
      union { ui4 v; __hip_bfloat162 h2[4]; } pk;
      pk.h2[0] = __float22bfloat162_rn(make_float2(xa[0], xa[1]));
      pk.h2[1] = __float22bfloat162_rn(make_float2(xa[2], xa[3]));
      pk.h2[2] = __float22bfloat162_rn(make_float2(xb[0], xb[1]));
      pk.h2[3] = __float22bfloat162_rn(make_float2(xb[2], xb[3]));
      *(ui4*)(cbW + xrow * LDK + xcg * 8) = pk.v;
    }

    ldsbar();   // single barrier per step (ping-pong buffers)
  };

#pragma unroll 1
  for (int t = 0; t < TT; t += 2) {
    stepf(t,     &cb[0][0], &cb[1][0]);
    stepf(t + 1, &cb[1][0], &cb[0][0]);
  }
}

extern "C" void kernel_launch(void* const* d_in, const int* in_sizes, int n_in,
                              void* d_out, int out_size, void* d_ws, size_t ws_size,
                              hipStream_t stream) {
  const float* inp    = (const float*)d_in[0];
  const float* hidden = (const float*)d_in[1];
  const float* Wih    = (const float*)d_in[2];
  const float* bih    = (const float*)d_in[3];
  const float* Wio    = (const float*)d_in[4];
  const float* bio    = (const float*)d_in[5];
  const float* act    = (const float*)d_in[6];
  float* out = (float*)d_out;
  rnn_fused<<<dim3(BBAT / NB), dim3(256), 0, stream>>>(
      inp, hidden, Wih, bih, Wio, bio, act, out);
}